// Round 8
// baseline (478.789 us; speedup 1.0000x reference)
//
#include <hip/hip_runtime.h>
#include <math.h>

// x: [8,512,32,32] fp32 | W_qkv: [1536,512,3,3] fp32 | W_out: [512,512,1,1]
// gamma/beta: [512] | out: [8,512,32,32] fp32
// G=8 heads, D=64 head dim, N=1024 seq (h*w), B=8

#define SMOOTH 1e-4f
#define BN_EPS 1e-5f

typedef __attribute__((ext_vector_type(8))) short bf16x8;
typedef __attribute__((ext_vector_type(4))) float f32x4;
typedef __attribute__((ext_vector_type(4))) unsigned int u32x4;
typedef __attribute__((ext_vector_type(4))) unsigned short u16x4;

__device__ inline unsigned short bf16rne(float f) {
  unsigned int u = __float_as_uint(f);
  u += 0x7fff + ((u >> 16) & 1);
  return (unsigned short)(u >> 16);
}
__device__ inline float fastrcp(float x) {
#if __has_builtin(__builtin_amdgcn_rcpf)
  return __builtin_amdgcn_rcpf(x);
#else
  return 1.0f / x;
#endif
}

// Async 16B global->LDS DMA (gfx950). LDS dest = wave-uniform base + lane*16.
typedef __attribute__((address_space(1))) void gvoid;
typedef __attribute__((address_space(3))) void lvoid;
__device__ __forceinline__ void async16(const void* g, void* l) {
  __builtin_amdgcn_global_load_lds((gvoid*)g, (lvoid*)l, 16, 0, 0);
}

// ---------------------------------------------------------------------------
// Repack W_qkv [co][ci][3][3] fp32 -> wqr [t][co][ci] bf16 via LDS tile.
// ---------------------------------------------------------------------------
__global__ void repack_w(const float* __restrict__ wq,
                         unsigned short* __restrict__ wqr) {
  __shared__ float Ws[2304];  // 256 pairs x 9 taps
  const int tid = threadIdx.x;
  const size_t pair0 = (size_t)blockIdx.x * 256;
  for (int off = tid; off < 576; off += 256)
    *(float4*)(Ws + off * 4) = *(const float4*)(wq + pair0 * 9 + off * 4);
  __syncthreads();
  // LDS read stride 9 (odd) -> conflict-free across lanes.
#pragma unroll
  for (int t = 0; t < 9; ++t)
    wqr[(size_t)t * 786432 + pair0 + tid] = bf16rne(Ws[tid * 9 + t]);
}

// ---------------------------------------------------------------------------
// Repack x [b][ci][p] fp32 -> xrp [b][34][34][ci] bf16 (zero-padded halo;
// border zeroed by hipMemsetAsync before this kernel). LDS tile transpose.
// ---------------------------------------------------------------------------
__global__ void repack_x(const float* __restrict__ x,
                         unsigned short* __restrict__ xrp) {
  __shared__ float Xs[64 * 132];  // rows padded to 132 floats
  const int tid = threadIdx.x;
  const int p0 = (blockIdx.x & 7) * 128;
  const int ci0 = ((blockIdx.x >> 3) & 7) * 64;
  const int b = blockIdx.x >> 6;
  for (int k = 0; k < 8; ++k) {
    int idx = tid + k * 256;  // 2048 float4s
    int c4 = idx & 31, row = idx >> 5;
    *(float4*)(Xs + row * 132 + c4 * 4) =
        *(const float4*)(x + ((size_t)(b * 512 + ci0 + row)) * 1024 + p0 + c4 * 4);
  }
  __syncthreads();
  const int pl = tid >> 1, half = tid & 1;
  const int p = p0 + pl;
  const int h = p >> 5, w = p & 31;
  unsigned short* dst =
      xrp + ((size_t)((b * 34 + h + 1) * 34 + w + 1)) * 512 + ci0 + half * 32;
#pragma unroll
  for (int v = 0; v < 8; ++v) {
    u16x4 pk;
#pragma unroll
    for (int e = 0; e < 4; ++e)
      pk[e] = bf16rne(Xs[(half * 32 + v * 4 + e) * 132 + pl]);
    *(u16x4*)(dst + v * 4) = pk;
  }
}

// Repack W_out fp32 -> bf16; block 0 also zeroes the BN stat accumulators.
__global__ void repack_wo(const float* __restrict__ wo,
                          unsigned short* __restrict__ wor,
                          float* __restrict__ sums, float* __restrict__ sumsq) {
  int idx = blockIdx.x * 256 + threadIdx.x;  // 262144
  wor[idx] = bf16rne(wo[idx]);
  if (blockIdx.x < 2) {
    sums[idx] = 0.f;
    sumsq[idx] = 0.f;
  }
}

// ---------------------------------------------------------------------------
// Kernel 1: 3x3 conv bf16 MFMA implicit GEMM (R3 tile: block 64co x 128n,
// 4 waves of 32co x 64n).  NEW vs R7:
//  * LDS in ci-granule PLANES: Wl[c4][t][co], Xl[c4][hh][wi] (16B granules).
//    Fragment reads stride 1 granule = 4 banks/lane -> 2-way max (free),
//    vs old row-stride-64B layout = 8-way conflict on every frag read.
//  * Staging via global_load_lds width=16 (async DMA, no VGPR round-trip);
//    plane layout keeps LDS dest contiguous in granule order as required.
//  * xrp is zero-padded -> no halo branches in staging.
// Fused qn/kn epilogue unchanged.
// ---------------------------------------------------------------------------
__global__ __launch_bounds__(256) void conv3x3_mfma(
    const unsigned short* __restrict__ wqr,
    const unsigned short* __restrict__ xrp,
    unsigned short* __restrict__ qt, unsigned short* __restrict__ kt,
    unsigned short* __restrict__ vt, float* __restrict__ qn,
    float* __restrict__ kn) {
  __shared__ __align__(16) unsigned short Wl[2304 * 8];  // 36864 B, [c4][t][co]
  __shared__ __align__(16) unsigned short Xl[816 * 8];   // 13056 B, [c4][hh][wi]
  __shared__ float Snl[128];                             // norm partials

  const int tid = threadIdx.x;
  const int lane = tid & 63;
  const int wave = tid >> 6;
  const int wco = (wave & 1) * 32;
  const int wn = (wave >> 1) * 64;
  const int l15 = lane & 15;
  const int quad = lane >> 4;
  const int h0 = blockIdx.x * 4;
  const int co0 = blockIdx.y * 64;
  const int b = blockIdx.z;

  f32x4 acc[2][4];
  for (int ma = 0; ma < 2; ++ma)
    for (int nb = 0; nb < 4; ++nb) acc[ma][nb] = (f32x4){0.f, 0.f, 0.f, 0.f};

  for (int ci0 = 0; ci0 < 512; ci0 += 32) {
    __syncthreads();  // prior iter's readers done
    // W: 2304 granules = 36 wave-chunks of 64; chunk c: c4=c/9 (plane),
    // t=c%9, co=lane. Source: 16B every 1KB (co-major stride).
#pragma unroll
    for (int j = 0; j < 9; ++j) {
      int c = wave + 4 * j;
      int c4 = c / 9;
      int t = c - c4 * 9;
      async16(wqr + ((size_t)(t * 1536 + co0) + lane) * 512 + ci0 + c4 * 8,
              Wl + (size_t)c * 512);
    }
    // X: 816 granules; per-lane decode g -> (c4, hh, wi); no halo branch.
#pragma unroll
    for (int j = 0; j < 3; ++j) {
      int c = wave + 4 * j;
      int g = c * 64 + lane;
      int c4 = g / 204;
      int rem = g - c4 * 204;
      int hh = rem / 34, wi = rem - hh * 34;
      async16(xrp + ((size_t)((b * 34 + h0 + hh) * 34 + wi)) * 512 + ci0 + c4 * 8,
              Xl + (size_t)c * 512);
    }
    if (wave == 0 && lane < 48) {  // tail granules 768..815 (plane c4=3)
      int g = 768 + lane;
      int rem = g - 612;  // 3*204
      int hh = rem / 34, wi = rem - hh * 34;
      async16(xrp + ((size_t)((b * 34 + h0 + hh) * 34 + wi)) * 512 + ci0 + 24,
              Xl + (size_t)768 * 8);
    }
    __syncthreads();  // drains vmcnt (global_load_lds) before reads

#pragma unroll
    for (int t = 0; t < 9; ++t) {
      const int ky = t / 3, kx = t - ky * 3;
      bf16x8 af[2], bfr[4];
#pragma unroll
      for (int ma = 0; ma < 2; ++ma)
        af[ma] = *(const bf16x8*)(
            Wl + ((size_t)(quad * 576 + t * 64 + wco + ma * 16 + l15)) * 8);
#pragma unroll
      for (int nb = 0; nb < 4; ++nb) {
        int n = wn + nb * 16 + l15;
        int hh = (n >> 5) + ky;
        int wi = (n & 31) + kx;
        bfr[nb] = *(const bf16x8*)(Xl + ((size_t)(quad * 204 + hh * 34 + wi)) * 8);
      }
#pragma unroll
      for (int ma = 0; ma < 2; ++ma)
#pragma unroll
        for (int nb = 0; nb < 4; ++nb)
          acc[ma][nb] = __builtin_amdgcn_mfma_f32_16x16x32_bf16(
              af[ma], bfr[nb], acc[ma][nb], 0, 0, 0);
    }
  }

  // Epilogue: C/D layout col(n)=lane&15, row(m)=quad*4+reg.
  const int sec = co0 >> 9;
  const int g = (co0 & 511) >> 6;
  const int bg = b * 8 + g;
  if (sec < 2) {
    unsigned short* dst = (sec == 0) ? qt : kt;
#pragma unroll
    for (int ma = 0; ma < 2; ++ma)
#pragma unroll
      for (int nb = 0; nb < 4; ++nb) {
        int n = wn + nb * 16 + l15;
        int p = (h0 + (n >> 5)) * 32 + (n & 31);
        int db = wco + ma * 16 + quad * 4;
        u16x4 pk;
#pragma unroll
        for (int r = 0; r < 4; ++r) pk[r] = bf16rne(acc[ma][nb][r]);
        *(u16x4*)(dst + ((size_t)bg * 1024 + p) * 64 + db) = pk;
      }
    // Fused row norms: per n, sum acc^2 over this wave's 32 d, combine the
    // wave pair (wco 0 + wco 32) via Snl, then sqrt to qn/kn.
    float ps[4];
#pragma unroll
    for (int nb = 0; nb < 4; ++nb) {
      float s = 0.f;
#pragma unroll
      for (int ma = 0; ma < 2; ++ma)
#pragma unroll
        for (int r = 0; r < 4; ++r) s = fmaf(acc[ma][nb][r], acc[ma][nb][r], s);
      s += __shfl_down(s, 32);
      s += __shfl_down(s, 16);
      ps[nb] = s;  // valid in quad==0 lanes
    }
    if (wco == 0 && quad == 0)
#pragma unroll
      for (int nb = 0; nb < 4; ++nb) Snl[wn + nb * 16 + l15] = ps[nb];
    __syncthreads();
    if (wco == 32 && quad == 0) {
      float* ndst = (sec == 0) ? qn : kn;
#pragma unroll
      for (int nb = 0; nb < 4; ++nb) {
        int n = wn + nb * 16 + l15;
        int p = (h0 + (n >> 5)) * 32 + (n & 31);
        ndst[bg * 1024 + p] = sqrtf(Snl[n] + ps[nb] + SMOOTH);
      }
    }
  } else {
#pragma unroll
    for (int ma = 0; ma < 2; ++ma)
#pragma unroll
      for (int nb = 0; nb < 4; ++nb) {
        int n = wn + nb * 16 + l15;
        int p = (h0 + (n >> 5)) * 32 + (n & 31);
#pragma unroll
        for (int r = 0; r < 4; ++r) {
          int d = wco + ma * 16 + quad * 4 + r;
          vt[((size_t)bg * 64 + d) * 1024 + p] = bf16rne(acc[ma][nb][r]);
        }
      }
  }
}

// ---------------------------------------------------------------------------
// Kernel 3: attention, bf16 MFMA. Block = 64 i x (b,g); 4 waves, 16 i each.
// ---------------------------------------------------------------------------
__global__ __launch_bounds__(256) void attn_mfma(
    const unsigned short* __restrict__ qt, const unsigned short* __restrict__ kt,
    const unsigned short* __restrict__ vt, const float* __restrict__ qn,
    const float* __restrict__ kn, unsigned short* __restrict__ aob) {
  __shared__ __align__(16) unsigned short Kl[64 * 72];  // [j][d]
  __shared__ __align__(16) unsigned short Vl[64 * 72];  // [d][j]
  __shared__ __align__(16) unsigned short Sl[64 * 72];  // [i][j], 16 rows/wave

  const int tid = threadIdx.x;
  const int lane = tid & 63, wave = tid >> 6;
  const int l15 = lane & 15, quad = lane >> 4;
  const int bg = blockIdx.x;  // fastest -> same-bg blocks share XCD L2
  const int i0 = blockIdx.y * 64;
  const int iw = i0 + wave * 16;
  const int b = bg >> 3, g = bg & 7;

  bf16x8 qf[2];
#pragma unroll
  for (int ks = 0; ks < 2; ++ks)
    qf[ks] = *(const bf16x8*)(
        qt + ((size_t)bg * 1024 + iw + l15) * 64 + ks * 32 + quad * 8);

  float qn_i[4];
#pragma unroll
  for (int r = 0; r < 4; ++r) qn_i[r] = qn[bg * 1024 + iw + quad * 4 + r];

  f32x4 oacc[4];
  for (int nf = 0; nf < 4; ++nf) oacc[nf] = (f32x4){0.f, 0.f, 0.f, 0.f};

  unsigned short* Sw = Sl + wave * 16 * 72;

  for (int jt = 0; jt < 16; ++jt) {
    const int j0 = jt * 64;
    __syncthreads();
    for (int idx = tid; idx < 512; idx += 256) {
      int c8 = idx & 7, row = idx >> 3;
      *(u32x4*)(Kl + row * 72 + c8 * 8) =
          *(const u32x4*)(kt + ((size_t)bg * 1024 + j0 + row) * 64 + c8 * 8);
      *(u32x4*)(Vl + row * 72 + c8 * 8) =
          *(const u32x4*)(vt + ((size_t)bg * 64 + row) * 1024 + j0 + c8 * 8);
    }
    __syncthreads();

    f32x4 sacc[4];
    for (int nb = 0; nb < 4; ++nb) sacc[nb] = (f32x4){0.f, 0.f, 0.f, 0.f};
#pragma unroll
    for (int ks = 0; ks < 2; ++ks) {
#pragma unroll
      for (int nb = 0; nb < 4; ++nb) {
        bf16x8 kf = *(const bf16x8*)(Kl + (l15 + 16 * nb) * 72 + ks * 32 + quad * 8);
        sacc[nb] = __builtin_amdgcn_mfma_f32_16x16x32_bf16(
            qf[ks], kf, sacc[nb], 0, 0, 0);
      }
    }

#pragma unroll
    for (int nb = 0; nb < 4; ++nb) {
      float kn_j = kn[bg * 1024 + j0 + l15 + 16 * nb];
#pragma unroll
      for (int r = 0; r < 4; ++r) {
        float s = sacc[nb][r] * fastrcp(fmaf(qn_i[r], kn_j, SMOOTH));
        Sw[(quad * 4 + r) * 72 + l15 + 16 * nb] = bf16rne(s);
      }
    }
    // Sw is wave-private: lgkmcnt orders write->read, no barrier needed.
#pragma unroll
    for (int ks2 = 0; ks2 < 2; ++ks2) {
      bf16x8 sa = *(const bf16x8*)(Sw + l15 * 72 + ks2 * 32 + quad * 8);
#pragma unroll
      for (int nf = 0; nf < 4; ++nf) {
        bf16x8 vb = *(const bf16x8*)(Vl + (l15 + 16 * nf) * 72 + ks2 * 32 + quad * 8);
        oacc[nf] = __builtin_amdgcn_mfma_f32_16x16x32_bf16(sa, vb, oacc[nf], 0, 0, 0);
      }
    }
  }

#pragma unroll
  for (int nf = 0; nf < 4; ++nf)
#pragma unroll
    for (int r = 0; r < 4; ++r) {
      int i = iw + quad * 4 + r;
      int d = l15 + 16 * nf;
      aob[((size_t)(b * 1024) + i) * 512 + g * 64 + d] = bf16rne(oacc[nf][r]);
    }
}

// ---------------------------------------------------------------------------
// Kernel 4: 1x1 conv bf16 MFMA (M=512co, N=8192p, K=512ci) + BN stats.
// Block 64co x 64p (grid 1024 = 4/CU), 4 waves of 32co x 32p.
// ---------------------------------------------------------------------------
__global__ __launch_bounds__(256) void conv1x1_mfma(
    const unsigned short* __restrict__ wor, const unsigned short* __restrict__ aob,
    float* __restrict__ y, float* __restrict__ sums, float* __restrict__ sumsq) {
  __shared__ __align__(16) unsigned short Wl[64 * 40];  // [co][ci]
  __shared__ __align__(16) unsigned short Bl[64 * 40];  // [p][ci]

  const int tid = threadIdx.x;
  const int lane = tid & 63, wave = tid >> 6;
  const int l15 = lane & 15, quad = lane >> 4;
  const int wco = (wave & 1) * 32;
  const int wp = (wave >> 1) * 32;
  const int p0 = blockIdx.x * 64;
  const int co0 = blockIdx.y * 64;
  const int b = blockIdx.z;

  f32x4 acc[2][2];
  for (int ma = 0; ma < 2; ++ma)
    for (int nb = 0; nb < 2; ++nb) acc[ma][nb] = (f32x4){0.f, 0.f, 0.f, 0.f};

  for (int ci0 = 0; ci0 < 512; ci0 += 32) {
    __syncthreads();
    {
      int c4 = tid & 3, co = tid >> 2;
      *(u32x4*)(Wl + co * 40 + c4 * 8) =
          *(const u32x4*)(wor + (size_t)(co0 + co) * 512 + ci0 + c4 * 8);
      *(u32x4*)(Bl + co * 40 + c4 * 8) =
          *(const u32x4*)(aob + ((size_t)(b * 1024) + p0 + co) * 512 + ci0 + c4 * 8);
    }
    __syncthreads();

    bf16x8 af[2], bf[2];
#pragma unroll
    for (int ma = 0; ma < 2; ++ma)
      af[ma] = *(const bf16x8*)(Wl + (wco + ma * 16 + l15) * 40 + quad * 8);
#pragma unroll
    for (int nb = 0; nb < 2; ++nb)
      bf[nb] = *(const bf16x8*)(Bl + (wp + nb * 16 + l15) * 40 + quad * 8);
#pragma unroll
    for (int ma = 0; ma < 2; ++ma)
#pragma unroll
      for (int nb = 0; nb < 2; ++nb)
        acc[ma][nb] = __builtin_amdgcn_mfma_f32_16x16x32_bf16(
            af[ma], bf[nb], acc[ma][nb], 0, 0, 0);
  }

#pragma unroll
  for (int ma = 0; ma < 2; ++ma)
#pragma unroll
    for (int r = 0; r < 4; ++r) {
      int co = co0 + wco + ma * 16 + quad * 4 + r;
      float s1 = 0.f, s2 = 0.f;
#pragma unroll
      for (int nb = 0; nb < 2; ++nb) {
        float v = acc[ma][nb][r];
        y[((size_t)(b * 512) + co) * 1024 + p0 + wp + nb * 16 + l15] = v;
        s1 += v;
        s2 = fmaf(v, v, s2);
      }
      for (int off = 8; off >= 1; off >>= 1) {
        s1 += __shfl_down(s1, off, 16);
        s2 += __shfl_down(s2, off, 16);
      }
      if (l15 == 0) {
        atomicAdd(&sums[co], s1);
        atomicAdd(&sumsq[co], s2);
      }
    }
}

// ---------------------------------------------------------------------------
// Kernel 5: BatchNorm (batch stats, biased var) + ReLU, float4.
// ---------------------------------------------------------------------------
__global__ void bn_kernel(const float* __restrict__ y,
                          const float* __restrict__ sums,
                          const float* __restrict__ sumsq,
                          const float* __restrict__ gamma,
                          const float* __restrict__ beta,
                          float* __restrict__ out) {
  int idx = blockIdx.x * 256 + threadIdx.x;  // 1048576 float4s
  int c = (idx >> 8) & 511;
  float4 v = ((const float4*)y)[idx];
  float mean = sums[c] * (1.f / 8192.f);
  float var = sumsq[c] * (1.f / 8192.f) - mean * mean;
  float sc = gamma[c] * rsqrtf(var + BN_EPS);
  float sh = beta[c] - mean * sc;
  float4 r;
  r.x = fmaxf(0.f, fmaf(v.x, sc, sh));
  r.y = fmaxf(0.f, fmaf(v.y, sc, sh));
  r.z = fmaxf(0.f, fmaf(v.z, sc, sh));
  r.w = fmaxf(0.f, fmaf(v.w, sc, sh));
  ((float4*)out)[idx] = r;
}

// ---------------------------------------------------------------------------
extern "C" void kernel_launch(void* const* d_in, const int* in_sizes, int n_in,
                              void* d_out, int out_size, void* d_ws,
                              size_t ws_size, hipStream_t stream) {
  const float* x = (const float*)d_in[0];
  const float* wq = (const float*)d_in[1];
  const float* wo = (const float*)d_in[2];
  const float* gamma = (const float*)d_in[3];
  const float* beta = (const float*)d_in[4];
  float* out = (float*)d_out;

  // Workspace layout (~75 MB, all 16B aligned)
  unsigned short* qt = (unsigned short*)d_ws;          // [64][1024][64]
  unsigned short* kt = qt + (size_t)4194304;
  unsigned short* vt = kt + (size_t)4194304;           // [64][64][1024]
  unsigned short* aob = vt + (size_t)4194304;          // [8][1024][512]
  unsigned short* wqr = aob + (size_t)4194304;         // [9][1536][512]
  unsigned short* wor = wqr + (size_t)7077888;         // [512][512]
  unsigned short* xrp = wor + (size_t)262144;          // [8][34][34][512] padded
  float* qn = (float*)(xrp + (size_t)4734976);         // [64][1024]
  float* kn = qn + 65536;
  float* y = kn + 65536;                               // [8][512][1024] fp32
  float* sums = y + (size_t)4194304;
  float* sumsq = sums + 512;

  // Zero padded-x halo (borders stay 0; repack_x fills the interior).
  hipMemsetAsync(xrp, 0, (size_t)4734976 * 2, stream);
  repack_w<<<dim3(3072), 256, 0, stream>>>(wq, wqr);
  repack_x<<<dim3(512), 256, 0, stream>>>(x, xrp);
  repack_wo<<<dim3(1024), 256, 0, stream>>>(wo, wor, sums, sumsq);
  conv3x3_mfma<<<dim3(8, 24, 8), 256, 0, stream>>>(wqr, xrp, qt, kt, vt, qn, kn);
  attn_mfma<<<dim3(64, 16), 256, 0, stream>>>(qt, kt, vt, qn, kn, aob);
  conv1x1_mfma<<<dim3(16, 8, 8), 256, 0, stream>>>(wor, aob, y, sums, sumsq);
  bn_kernel<<<dim3(4096), 256, 0, stream>>>(y, sums, sumsq, gamma, beta, out);
}

// Round 9
// 303.442 us; speedup vs baseline: 1.5779x; 1.5779x over previous
//
#include <hip/hip_runtime.h>
#include <math.h>

// x: [8,512,32,32] fp32 | W_qkv: [1536,512,3,3] fp32 | W_out: [512,512,1,1]
// gamma/beta: [512] | out: [8,512,32,32] fp32
// G=8 heads, D=64 head dim, N=1024 seq (h*w), B=8

#define SMOOTH 1e-4f
#define BN_EPS 1e-5f

typedef __attribute__((ext_vector_type(8))) short bf16x8;
typedef __attribute__((ext_vector_type(4))) float f32x4;
typedef __attribute__((ext_vector_type(4))) unsigned int u32x4;
typedef __attribute__((ext_vector_type(4))) unsigned short u16x4;

__device__ inline unsigned short bf16rne(float f) {
  unsigned int u = __float_as_uint(f);
  u += 0x7fff + ((u >> 16) & 1);
  return (unsigned short)(u >> 16);
}
__device__ inline float fastrcp(float x) {
#if __has_builtin(__builtin_amdgcn_rcpf)
  return __builtin_amdgcn_rcpf(x);
#else
  return 1.0f / x;
#endif
}

// Async 16B global->LDS DMA (gfx950). LDS dest = wave-uniform base + lane*16.
// RULE (R8 lesson): lane gptr MUST be base + lane*16 (contiguous 1KB/wave),
// else ~4-5x HBM overfetch.
typedef __attribute__((address_space(1))) void gvoid;
typedef __attribute__((address_space(3))) void lvoid;
__device__ __forceinline__ void async16(const void* g, void* l) {
  __builtin_amdgcn_global_load_lds((gvoid*)g, (lvoid*)l, 16, 0, 0);
}

// ---------------------------------------------------------------------------
// Repack W_qkv [co][ci][3][3] fp32 -> wqr2 in conv-LDS granule order:
//   [ci0c:16][cotile:24][c4:4][t:9][co:64][e:8]   (18432 hw per (ci0c,cotile))
// so conv staging is a straight contiguous 36KB copy per K-iter.
// ---------------------------------------------------------------------------
__global__ void repack_w(const float* __restrict__ wq,
                         unsigned short* __restrict__ wqr2) {
  __shared__ float Ws[2304];  // 256 pairs x 9 taps
  const int tid = threadIdx.x;
  const size_t pair0 = (size_t)blockIdx.x * 256;
  for (int off = tid; off < 576; off += 256)
    *(float4*)(Ws + off * 4) = *(const float4*)(wq + pair0 * 9 + off * 4);
  __syncthreads();
  const int co = (int)(pair0 >> 9);        // fixed per block
  const int ci = (int)(pair0 & 511) + tid; // ciBase in {0,256}
  const int cotile = co >> 6, co_l = co & 63;
  const int ci0c = ci >> 5, c4 = (ci >> 3) & 3, e = ci & 7;
#pragma unroll
  for (int t = 0; t < 9; ++t) {
    size_t o = (size_t)(ci0c * 24 + cotile) * 18432 +
               (size_t)((c4 * 9 + t) * 64 + co_l) * 8 + e;
    wqr2[o] = bf16rne(Ws[tid * 9 + t]);
  }
}

// ---------------------------------------------------------------------------
// Repack x [b][ci][p] fp32 -> xrp2 [ci0c:16][c4:4][b:8][h:34][w:34][e:8] bf16
// (zero-padded halo; whole buffer memset 0 first). LDS tile transpose.
// ---------------------------------------------------------------------------
__global__ void repack_x(const float* __restrict__ x,
                         unsigned short* __restrict__ xrp2) {
  __shared__ float Xs[64 * 132];  // rows padded to 132 floats
  const int tid = threadIdx.x;
  const int p0 = (blockIdx.x & 7) * 128;
  const int ci0 = ((blockIdx.x >> 3) & 7) * 64;
  const int b = blockIdx.x >> 6;
  for (int k = 0; k < 8; ++k) {
    int idx = tid + k * 256;  // 2048 float4s
    int c4 = idx & 31, row = idx >> 5;
    *(float4*)(Xs + row * 132 + c4 * 4) =
        *(const float4*)(x + ((size_t)(b * 512 + ci0 + row)) * 1024 + p0 + c4 * 4);
  }
  __syncthreads();
  const int pl = tid >> 1, half = tid & 1;
  const int p = p0 + pl;
  const int h = p >> 5, w = p & 31;
#pragma unroll
  for (int v = 0; v < 8; ++v) {
    u16x4 pk;
#pragma unroll
    for (int e = 0; e < 4; ++e)
      pk[e] = bf16rne(Xs[(half * 32 + v * 4 + e) * 132 + pl]);
    int cc = ci0 + half * 32 + v * 4;
    int ci0c = cc >> 5, c4 = (cc >> 3) & 3, e0 = cc & 7;  // e0 in {0,4}
    size_t gran = (size_t)((ci0c * 4 + c4) * 8 + b) * 1156 + (h + 1) * 34 + (w + 1);
    *(u16x4*)(xrp2 + gran * 8 + e0) = pk;
  }
}

// Repack W_out fp32 -> bf16; block 0 also zeroes the BN stat accumulators.
__global__ void repack_wo(const float* __restrict__ wo,
                          unsigned short* __restrict__ wor,
                          float* __restrict__ sums, float* __restrict__ sumsq) {
  int idx = blockIdx.x * 256 + threadIdx.x;  // 262144
  wor[idx] = bf16rne(wo[idx]);
  if (blockIdx.x < 2) {
    sums[idx] = 0.f;
    sumsq[idx] = 0.f;
  }
}

// ---------------------------------------------------------------------------
// Kernel 1: 3x3 conv bf16 MFMA implicit GEMM. Block 64co x 128n (4h x 32w),
// 4 waves of 32co x 64n. LDS plane layouts, staged by async DMA where every
// instruction is a contiguous 1KB wave read (global layout == LDS layout):
//   Wl[c4][t][co] granules  <- wqr2 36KB contiguous per (K-iter, co-tile)
//   Xl[c4][hh*34+wi] (256-granule plane stride) <- xrp2 plane runs
// Frag reads: lane stride 16B = 4 banks -> <=2-way (free).
// Fused qn/kn epilogue unchanged.
// ---------------------------------------------------------------------------
__global__ __launch_bounds__(256) void conv3x3_mfma(
    const unsigned short* __restrict__ wqr2,
    const unsigned short* __restrict__ xrp2,
    unsigned short* __restrict__ qt, unsigned short* __restrict__ kt,
    unsigned short* __restrict__ vt, float* __restrict__ qn,
    float* __restrict__ kn) {
  __shared__ __align__(16) unsigned short Wl[2304 * 8];  // 36864 B
  __shared__ __align__(16) unsigned short Xl[4 * 256 * 8];  // 16384 B
  __shared__ float Snl[128];                             // norm partials

  const int tid = threadIdx.x;
  const int lane = tid & 63;
  const int wave = tid >> 6;
  const int wco = (wave & 1) * 32;
  const int wn = (wave >> 1) * 64;
  const int l15 = lane & 15;
  const int quad = lane >> 4;
  const int h0 = blockIdx.x * 4;
  const int co0 = blockIdx.y * 64;
  const int b = blockIdx.z;

  f32x4 acc[2][4];
  for (int ma = 0; ma < 2; ++ma)
    for (int nb = 0; nb < 4; ++nb) acc[ma][nb] = (f32x4){0.f, 0.f, 0.f, 0.f};

  for (int ci0 = 0; ci0 < 512; ci0 += 32) {
    const int ci0c = ci0 >> 5;
    __syncthreads();  // prior iter's readers done
    // W: 36 x 1KB contiguous wave reads (9 per wave).
    const unsigned short* wsrc =
        wqr2 + (size_t)(ci0c * 24 + (co0 >> 6)) * 18432;
    {
      int cbase = wave * 9;
#pragma unroll
      for (int j = 0; j < 9; ++j) {
        int c = cbase + j;
        async16(wsrc + (size_t)c * 512 + lane * 8, Wl + (size_t)c * 512);
      }
    }
    // X: plane w per wave; 4 x 1KB contiguous reads (last overlaps 52 junk
    // granules into unread LDS slots; xrp2 is padded at the end).
    const unsigned short* xsrc =
        xrp2 + ((size_t)((ci0c * 4 + wave) * 8 + b) * 1156 + h0 * 34) * 8;
#pragma unroll
    for (int j = 0; j < 4; ++j)
      async16(xsrc + (size_t)j * 512 + lane * 8,
              Xl + (size_t)(wave * 256 + j * 64) * 8);
    __syncthreads();  // drains vmcnt before frag reads

#pragma unroll
    for (int t = 0; t < 9; ++t) {
      const int ky = t / 3, kx = t - ky * 3;
      bf16x8 af[2], bfr[4];
#pragma unroll
      for (int ma = 0; ma < 2; ++ma)
        af[ma] = *(const bf16x8*)(
            Wl + (size_t)((quad * 9 + t) * 64 + wco + ma * 16 + l15) * 8);
#pragma unroll
      for (int nb = 0; nb < 4; ++nb) {
        int n = wn + nb * 16 + l15;
        int hh = (n >> 5) + ky;
        int wi = (n & 31) + kx;
        bfr[nb] = *(const bf16x8*)(Xl + (size_t)(quad * 256 + hh * 34 + wi) * 8);
      }
#pragma unroll
      for (int ma = 0; ma < 2; ++ma)
#pragma unroll
        for (int nb = 0; nb < 4; ++nb)
          acc[ma][nb] = __builtin_amdgcn_mfma_f32_16x16x32_bf16(
              af[ma], bfr[nb], acc[ma][nb], 0, 0, 0);
    }
  }

  // Epilogue: C/D layout col(n)=lane&15, row(m)=quad*4+reg.
  const int sec = co0 >> 9;
  const int g = (co0 & 511) >> 6;
  const int bg = b * 8 + g;
  if (sec < 2) {
    unsigned short* dst = (sec == 0) ? qt : kt;
#pragma unroll
    for (int ma = 0; ma < 2; ++ma)
#pragma unroll
      for (int nb = 0; nb < 4; ++nb) {
        int n = wn + nb * 16 + l15;
        int p = (h0 + (n >> 5)) * 32 + (n & 31);
        int db = wco + ma * 16 + quad * 4;
        u16x4 pk;
#pragma unroll
        for (int r = 0; r < 4; ++r) pk[r] = bf16rne(acc[ma][nb][r]);
        *(u16x4*)(dst + ((size_t)bg * 1024 + p) * 64 + db) = pk;
      }
    // Fused row norms: per n, sum acc^2 over this wave's 32 d, combine the
    // wave pair (wco 0 + wco 32) via Snl, then sqrt to qn/kn.
    float ps[4];
#pragma unroll
    for (int nb = 0; nb < 4; ++nb) {
      float s = 0.f;
#pragma unroll
      for (int ma = 0; ma < 2; ++ma)
#pragma unroll
        for (int r = 0; r < 4; ++r) s = fmaf(acc[ma][nb][r], acc[ma][nb][r], s);
      s += __shfl_down(s, 32);
      s += __shfl_down(s, 16);
      ps[nb] = s;  // valid in quad==0 lanes
    }
    if (wco == 0 && quad == 0)
#pragma unroll
      for (int nb = 0; nb < 4; ++nb) Snl[wn + nb * 16 + l15] = ps[nb];
    __syncthreads();
    if (wco == 32 && quad == 0) {
      float* ndst = (sec == 0) ? qn : kn;
#pragma unroll
      for (int nb = 0; nb < 4; ++nb) {
        int n = wn + nb * 16 + l15;
        int p = (h0 + (n >> 5)) * 32 + (n & 31);
        ndst[bg * 1024 + p] = sqrtf(Snl[n] + ps[nb] + SMOOTH);
      }
    }
  } else {
#pragma unroll
    for (int ma = 0; ma < 2; ++ma)
#pragma unroll
      for (int nb = 0; nb < 4; ++nb) {
        int n = wn + nb * 16 + l15;
        int p = (h0 + (n >> 5)) * 32 + (n & 31);
#pragma unroll
        for (int r = 0; r < 4; ++r) {
          int d = wco + ma * 16 + quad * 4 + r;
          vt[((size_t)bg * 64 + d) * 1024 + p] = bf16rne(acc[ma][nb][r]);
        }
      }
  }
}

// ---------------------------------------------------------------------------
// Kernel 3: attention, bf16 MFMA. Block = 64 i x (b,g); 4 waves, 16 i each.
// ---------------------------------------------------------------------------
__global__ __launch_bounds__(256) void attn_mfma(
    const unsigned short* __restrict__ qt, const unsigned short* __restrict__ kt,
    const unsigned short* __restrict__ vt, const float* __restrict__ qn,
    const float* __restrict__ kn, unsigned short* __restrict__ aob) {
  __shared__ __align__(16) unsigned short Kl[64 * 72];  // [j][d]
  __shared__ __align__(16) unsigned short Vl[64 * 72];  // [d][j]
  __shared__ __align__(16) unsigned short Sl[64 * 72];  // [i][j], 16 rows/wave

  const int tid = threadIdx.x;
  const int lane = tid & 63, wave = tid >> 6;
  const int l15 = lane & 15, quad = lane >> 4;
  const int bg = blockIdx.x;  // fastest -> same-bg blocks share XCD L2
  const int i0 = blockIdx.y * 64;
  const int iw = i0 + wave * 16;
  const int b = bg >> 3, g = bg & 7;

  bf16x8 qf[2];
#pragma unroll
  for (int ks = 0; ks < 2; ++ks)
    qf[ks] = *(const bf16x8*)(
        qt + ((size_t)bg * 1024 + iw + l15) * 64 + ks * 32 + quad * 8);

  float qn_i[4];
#pragma unroll
  for (int r = 0; r < 4; ++r) qn_i[r] = qn[bg * 1024 + iw + quad * 4 + r];

  f32x4 oacc[4];
  for (int nf = 0; nf < 4; ++nf) oacc[nf] = (f32x4){0.f, 0.f, 0.f, 0.f};

  unsigned short* Sw = Sl + wave * 16 * 72;

  for (int jt = 0; jt < 16; ++jt) {
    const int j0 = jt * 64;
    __syncthreads();
    for (int idx = tid; idx < 512; idx += 256) {
      int c8 = idx & 7, row = idx >> 3;
      *(u32x4*)(Kl + row * 72 + c8 * 8) =
          *(const u32x4*)(kt + ((size_t)bg * 1024 + j0 + row) * 64 + c8 * 8);
      *(u32x4*)(Vl + row * 72 + c8 * 8) =
          *(const u32x4*)(vt + ((size_t)bg * 64 + row) * 1024 + j0 + c8 * 8);
    }
    __syncthreads();

    f32x4 sacc[4];
    for (int nb = 0; nb < 4; ++nb) sacc[nb] = (f32x4){0.f, 0.f, 0.f, 0.f};
#pragma unroll
    for (int ks = 0; ks < 2; ++ks) {
#pragma unroll
      for (int nb = 0; nb < 4; ++nb) {
        bf16x8 kf = *(const bf16x8*)(Kl + (l15 + 16 * nb) * 72 + ks * 32 + quad * 8);
        sacc[nb] = __builtin_amdgcn_mfma_f32_16x16x32_bf16(
            qf[ks], kf, sacc[nb], 0, 0, 0);
      }
    }

#pragma unroll
    for (int nb = 0; nb < 4; ++nb) {
      float kn_j = kn[bg * 1024 + j0 + l15 + 16 * nb];
#pragma unroll
      for (int r = 0; r < 4; ++r) {
        float s = sacc[nb][r] * fastrcp(fmaf(qn_i[r], kn_j, SMOOTH));
        Sw[(quad * 4 + r) * 72 + l15 + 16 * nb] = bf16rne(s);
      }
    }
    // Sw is wave-private: lgkmcnt orders write->read, no barrier needed.
#pragma unroll
    for (int ks2 = 0; ks2 < 2; ++ks2) {
      bf16x8 sa = *(const bf16x8*)(Sw + l15 * 72 + ks2 * 32 + quad * 8);
#pragma unroll
      for (int nf = 0; nf < 4; ++nf) {
        bf16x8 vb = *(const bf16x8*)(Vl + (l15 + 16 * nf) * 72 + ks2 * 32 + quad * 8);
        oacc[nf] = __builtin_amdgcn_mfma_f32_16x16x32_bf16(sa, vb, oacc[nf], 0, 0, 0);
      }
    }
  }

#pragma unroll
  for (int nf = 0; nf < 4; ++nf)
#pragma unroll
    for (int r = 0; r < 4; ++r) {
      int i = iw + quad * 4 + r;
      int d = l15 + 16 * nf;
      aob[((size_t)(b * 1024) + i) * 512 + g * 64 + d] = bf16rne(oacc[nf][r]);
    }
}

// ---------------------------------------------------------------------------
// Kernel 4: 1x1 conv bf16 MFMA (M=512co, N=8192p, K=512ci) + BN stats.
// Block 64co x 64p (grid 1024 = 4/CU), 4 waves of 32co x 32p.
// ---------------------------------------------------------------------------
__global__ __launch_bounds__(256) void conv1x1_mfma(
    const unsigned short* __restrict__ wor, const unsigned short* __restrict__ aob,
    float* __restrict__ y, float* __restrict__ sums, float* __restrict__ sumsq) {
  __shared__ __align__(16) unsigned short Wl[64 * 40];  // [co][ci]
  __shared__ __align__(16) unsigned short Bl[64 * 40];  // [p][ci]

  const int tid = threadIdx.x;
  const int lane = tid & 63, wave = tid >> 6;
  const int l15 = lane & 15, quad = lane >> 4;
  const int wco = (wave & 1) * 32;
  const int wp = (wave >> 1) * 32;
  const int p0 = blockIdx.x * 64;
  const int co0 = blockIdx.y * 64;
  const int b = blockIdx.z;

  f32x4 acc[2][2];
  for (int ma = 0; ma < 2; ++ma)
    for (int nb = 0; nb < 2; ++nb) acc[ma][nb] = (f32x4){0.f, 0.f, 0.f, 0.f};

  for (int ci0 = 0; ci0 < 512; ci0 += 32) {
    __syncthreads();
    {
      int c4 = tid & 3, co = tid >> 2;
      *(u32x4*)(Wl + co * 40 + c4 * 8) =
          *(const u32x4*)(wor + (size_t)(co0 + co) * 512 + ci0 + c4 * 8);
      *(u32x4*)(Bl + co * 40 + c4 * 8) =
          *(const u32x4*)(aob + ((size_t)(b * 1024) + p0 + co) * 512 + ci0 + c4 * 8);
    }
    __syncthreads();

    bf16x8 af[2], bf[2];
#pragma unroll
    for (int ma = 0; ma < 2; ++ma)
      af[ma] = *(const bf16x8*)(Wl + (wco + ma * 16 + l15) * 40 + quad * 8);
#pragma unroll
    for (int nb = 0; nb < 2; ++nb)
      bf[nb] = *(const bf16x8*)(Bl + (wp + nb * 16 + l15) * 40 + quad * 8);
#pragma unroll
    for (int ma = 0; ma < 2; ++ma)
#pragma unroll
      for (int nb = 0; nb < 2; ++nb)
        acc[ma][nb] = __builtin_amdgcn_mfma_f32_16x16x32_bf16(
            af[ma], bf[nb], acc[ma][nb], 0, 0, 0);
  }

#pragma unroll
  for (int ma = 0; ma < 2; ++ma)
#pragma unroll
    for (int r = 0; r < 4; ++r) {
      int co = co0 + wco + ma * 16 + quad * 4 + r;
      float s1 = 0.f, s2 = 0.f;
#pragma unroll
      for (int nb = 0; nb < 2; ++nb) {
        float v = acc[ma][nb][r];
        y[((size_t)(b * 512) + co) * 1024 + p0 + wp + nb * 16 + l15] = v;
        s1 += v;
        s2 = fmaf(v, v, s2);
      }
      for (int off = 8; off >= 1; off >>= 1) {
        s1 += __shfl_down(s1, off, 16);
        s2 += __shfl_down(s2, off, 16);
      }
      if (l15 == 0) {
        atomicAdd(&sums[co], s1);
        atomicAdd(&sumsq[co], s2);
      }
    }
}

// ---------------------------------------------------------------------------
// Kernel 5: BatchNorm (batch stats, biased var) + ReLU, float4.
// ---------------------------------------------------------------------------
__global__ void bn_kernel(const float* __restrict__ y,
                          const float* __restrict__ sums,
                          const float* __restrict__ sumsq,
                          const float* __restrict__ gamma,
                          const float* __restrict__ beta,
                          float* __restrict__ out) {
  int idx = blockIdx.x * 256 + threadIdx.x;  // 1048576 float4s
  int c = (idx >> 8) & 511;
  float4 v = ((const float4*)y)[idx];
  float mean = sums[c] * (1.f / 8192.f);
  float var = sumsq[c] * (1.f / 8192.f) - mean * mean;
  float sc = gamma[c] * rsqrtf(var + BN_EPS);
  float sh = beta[c] - mean * sc;
  float4 r;
  r.x = fmaxf(0.f, fmaf(v.x, sc, sh));
  r.y = fmaxf(0.f, fmaf(v.y, sc, sh));
  r.z = fmaxf(0.f, fmaf(v.z, sc, sh));
  r.w = fmaxf(0.f, fmaf(v.w, sc, sh));
  ((float4*)out)[idx] = r;
}

// ---------------------------------------------------------------------------
extern "C" void kernel_launch(void* const* d_in, const int* in_sizes, int n_in,
                              void* d_out, int out_size, void* d_ws,
                              size_t ws_size, hipStream_t stream) {
  const float* x = (const float*)d_in[0];
  const float* wq = (const float*)d_in[1];
  const float* wo = (const float*)d_in[2];
  const float* gamma = (const float*)d_in[3];
  const float* beta = (const float*)d_in[4];
  float* out = (float*)d_out;

  // Workspace layout (~75 MB, all 16B aligned)
  unsigned short* qt = (unsigned short*)d_ws;          // [64][1024][64]
  unsigned short* kt = qt + (size_t)4194304;
  unsigned short* vt = kt + (size_t)4194304;           // [64][64][1024]
  unsigned short* aob = vt + (size_t)4194304;          // [8][1024][512]
  unsigned short* wqr2 = aob + (size_t)4194304;        // [16][24][4][9][64][8]
  unsigned short* wor = wqr2 + (size_t)7077888;        // [512][512]
  unsigned short* xrp2 = wor + (size_t)262144;         // [16][4][8][34][34][8]+pad
  float* qn = (float*)(xrp2 + (size_t)4736000);        // [64][1024]
  float* kn = qn + 65536;
  float* y = kn + 65536;                               // [8][512][1024] fp32
  float* sums = y + (size_t)4194304;
  float* sumsq = sums + 512;

  // Zero padded-x buffer (borders stay 0; repack_x fills the interior).
  hipMemsetAsync(xrp2, 0, (size_t)4736000 * 2, stream);
  repack_w<<<dim3(3072), 256, 0, stream>>>(wq, wqr2);
  repack_x<<<dim3(512), 256, 0, stream>>>(x, xrp2);
  repack_wo<<<dim3(1024), 256, 0, stream>>>(wo, wor, sums, sumsq);
  conv3x3_mfma<<<dim3(8, 24, 8), 256, 0, stream>>>(wqr2, xrp2, qt, kt, vt, qn, kn);
  attn_mfma<<<dim3(64, 16), 256, 0, stream>>>(qt, kt, vt, qn, kn, aob);
  conv1x1_mfma<<<dim3(16, 8, 8), 256, 0, stream>>>(wor, aob, y, sums, sumsq);
  bn_kernel<<<dim3(4096), 256, 0, stream>>>(y, sums, sumsq, gamma, beta, out);
}

// Round 10
// 293.428 us; speedup vs baseline: 1.6317x; 1.0341x over previous
//
#include <hip/hip_runtime.h>
#include <math.h>

// x: [8,512,32,32] fp32 | W_qkv: [1536,512,3,3] fp32 | W_out: [512,512,1,1]
// gamma/beta: [512] | out: [8,512,32,32] fp32
// G=8 heads, D=64 head dim, N=1024 seq (h*w), B=8

#define SMOOTH 1e-4f
#define BN_EPS 1e-5f

typedef __attribute__((ext_vector_type(8))) short bf16x8;
typedef __attribute__((ext_vector_type(8))) unsigned short u16x8;
typedef __attribute__((ext_vector_type(4))) float f32x4;
typedef __attribute__((ext_vector_type(4))) unsigned int u32x4;
typedef __attribute__((ext_vector_type(4))) unsigned short u16x4;

__device__ inline unsigned short bf16rne(float f) {
  unsigned int u = __float_as_uint(f);
  u += 0x7fff + ((u >> 16) & 1);
  return (unsigned short)(u >> 16);
}
__device__ inline float b2f(unsigned short u) {
  return __uint_as_float((unsigned int)u << 16);
}

// Async 16B global->LDS DMA (gfx950). LDS dest = wave-uniform base + lane*16.
// RULE (R8 lesson): lane gptr MUST be base + lane*16 (contiguous 1KB/wave),
// else ~4-5x HBM overfetch.
typedef __attribute__((address_space(1))) void gvoid;
typedef __attribute__((address_space(3))) void lvoid;
__device__ __forceinline__ void async16(const void* g, void* l) {
  __builtin_amdgcn_global_load_lds((gvoid*)g, (lvoid*)l, 16, 0, 0);
}

// ---------------------------------------------------------------------------
// Repack W_qkv [co][ci][3][3] fp32 -> wqr2 in conv-LDS granule order:
//   [ci0c:16][cotile:24][c4:4][t:9][co:64][e:8]
// 16B vector stores (R10: was 9 scalar 2B stores/thread).
// ---------------------------------------------------------------------------
__global__ void repack_w(const float* __restrict__ wq,
                         unsigned short* __restrict__ wqr2) {
  __shared__ float Ws[2304];  // 256 pairs x 9 taps
  const int tid = threadIdx.x;
  const size_t pair0 = (size_t)blockIdx.x * 256;
  for (int off = tid; off < 576; off += 256)
    *(float4*)(Ws + off * 4) = *(const float4*)(wq + pair0 * 9 + off * 4);
  __syncthreads();
  const int co = (int)(pair0 >> 9);         // fixed per block
  const int ciBase = (int)(pair0 & 511);    // 0 or 256
  const int cotile = co >> 6, co_l = co & 63;
  for (int idx = tid; idx < 288; idx += 256) {
    int t = idx >> 5;    // 0..8
    int oct = idx & 31;  // 0..31 -> 8 consecutive ci
    int ci = ciBase + oct * 8;
    int ci0c = ci >> 5, c4 = oct & 3;
    u16x8 pk;
#pragma unroll
    for (int e = 0; e < 8; ++e) pk[e] = bf16rne(Ws[(oct * 8 + e) * 9 + t]);
    size_t o = (size_t)(ci0c * 24 + cotile) * 18432 +
               (size_t)((c4 * 9 + t) * 64 + co_l) * 8;
    *(u16x8*)(wqr2 + o) = pk;
  }
}

// ---------------------------------------------------------------------------
// Repack x [b][ci][p] fp32 -> xrp2 [ci0c:16][c4:4][b:8][h:34][w:34][e:8] bf16
// (zero-padded halo; whole buffer memset 0 first). LDS tile transpose.
// ---------------------------------------------------------------------------
__global__ void repack_x(const float* __restrict__ x,
                         unsigned short* __restrict__ xrp2) {
  __shared__ float Xs[64 * 132];  // rows padded to 132 floats
  const int tid = threadIdx.x;
  const int p0 = (blockIdx.x & 7) * 128;
  const int ci0 = ((blockIdx.x >> 3) & 7) * 64;
  const int b = blockIdx.x >> 6;
  for (int k = 0; k < 8; ++k) {
    int idx = tid + k * 256;  // 2048 float4s
    int c4 = idx & 31, row = idx >> 5;
    *(float4*)(Xs + row * 132 + c4 * 4) =
        *(const float4*)(x + ((size_t)(b * 512 + ci0 + row)) * 1024 + p0 + c4 * 4);
  }
  __syncthreads();
  const int pl = tid >> 1, half = tid & 1;
  const int p = p0 + pl;
  const int h = p >> 5, w = p & 31;
#pragma unroll
  for (int v = 0; v < 8; ++v) {
    u16x4 pk;
#pragma unroll
    for (int e = 0; e < 4; ++e)
      pk[e] = bf16rne(Xs[(half * 32 + v * 4 + e) * 132 + pl]);
    int cc = ci0 + half * 32 + v * 4;
    int ci0c = cc >> 5, c4 = (cc >> 3) & 3, e0 = cc & 7;  // e0 in {0,4}
    size_t gran = (size_t)((ci0c * 4 + c4) * 8 + b) * 1156 + (h + 1) * 34 + (w + 1);
    *(u16x4*)(xrp2 + gran * 8 + e0) = pk;
  }
}

// Repack W_out fp32 -> bf16; block 0 also zeroes the BN stat accumulators.
__global__ void repack_wo(const float* __restrict__ wo,
                          unsigned short* __restrict__ wor,
                          float* __restrict__ sums, float* __restrict__ sumsq) {
  int idx = blockIdx.x * 256 + threadIdx.x;  // 262144
  wor[idx] = bf16rne(wo[idx]);
  if (blockIdx.x < 2) {
    sums[idx] = 0.f;
    sumsq[idx] = 0.f;
  }
}

// ---------------------------------------------------------------------------
// Kernel 1: 3x3 conv bf16 MFMA implicit GEMM. Block 64co x 128n (4h x 32w),
// 4 waves of 32co x 64n. LDS plane layouts, staged by async DMA where every
// instruction is a contiguous 1KB wave read (global layout == LDS layout).
// Frag reads: lane stride 16B = 4 banks -> <=2-way (free; measured 0 conflicts).
// Fused epilogue stores RECIPROCAL norms rqn=rsqrt(sum+SMOOTH) (R10) so the
// attention normalize needs no rcp.
// ---------------------------------------------------------------------------
__global__ __launch_bounds__(256) void conv3x3_mfma(
    const unsigned short* __restrict__ wqr2,
    const unsigned short* __restrict__ xrp2,
    unsigned short* __restrict__ qt, unsigned short* __restrict__ kt,
    unsigned short* __restrict__ vt, float* __restrict__ rqn,
    float* __restrict__ rkn) {
  __shared__ __align__(16) unsigned short Wl[2304 * 8];     // 36864 B
  __shared__ __align__(16) unsigned short Xl[4 * 256 * 8];  // 16384 B
  __shared__ float Snl[128];                                // norm partials

  const int tid = threadIdx.x;
  const int lane = tid & 63;
  const int wave = tid >> 6;
  const int wco = (wave & 1) * 32;
  const int wn = (wave >> 1) * 64;
  const int l15 = lane & 15;
  const int quad = lane >> 4;
  const int h0 = blockIdx.x * 4;
  const int co0 = blockIdx.y * 64;
  const int b = blockIdx.z;

  f32x4 acc[2][4];
  for (int ma = 0; ma < 2; ++ma)
    for (int nb = 0; nb < 4; ++nb) acc[ma][nb] = (f32x4){0.f, 0.f, 0.f, 0.f};

  for (int ci0 = 0; ci0 < 512; ci0 += 32) {
    const int ci0c = ci0 >> 5;
    __syncthreads();  // prior iter's readers done
    // W: 36 x 1KB contiguous wave reads (9 per wave).
    const unsigned short* wsrc =
        wqr2 + (size_t)(ci0c * 24 + (co0 >> 6)) * 18432;
    {
      int cbase = wave * 9;
#pragma unroll
      for (int j = 0; j < 9; ++j) {
        int c = cbase + j;
        async16(wsrc + (size_t)c * 512 + lane * 8, Wl + (size_t)c * 512);
      }
    }
    // X: plane w per wave; 4 x 1KB contiguous reads (last overlaps 52 junk
    // granules into unread LDS slots; xrp2 is padded at the end).
    const unsigned short* xsrc =
        xrp2 + ((size_t)((ci0c * 4 + wave) * 8 + b) * 1156 + h0 * 34) * 8;
#pragma unroll
    for (int j = 0; j < 4; ++j)
      async16(xsrc + (size_t)j * 512 + lane * 8,
              Xl + (size_t)(wave * 256 + j * 64) * 8);
    __syncthreads();  // drains vmcnt before frag reads

#pragma unroll
    for (int t = 0; t < 9; ++t) {
      const int ky = t / 3, kx = t - ky * 3;
      bf16x8 af[2], bfr[4];
#pragma unroll
      for (int ma = 0; ma < 2; ++ma)
        af[ma] = *(const bf16x8*)(
            Wl + (size_t)((quad * 9 + t) * 64 + wco + ma * 16 + l15) * 8);
#pragma unroll
      for (int nb = 0; nb < 4; ++nb) {
        int n = wn + nb * 16 + l15;
        int hh = (n >> 5) + ky;
        int wi = (n & 31) + kx;
        bfr[nb] = *(const bf16x8*)(Xl + (size_t)(quad * 256 + hh * 34 + wi) * 8);
      }
#pragma unroll
      for (int ma = 0; ma < 2; ++ma)
#pragma unroll
        for (int nb = 0; nb < 4; ++nb)
          acc[ma][nb] = __builtin_amdgcn_mfma_f32_16x16x32_bf16(
              af[ma], bfr[nb], acc[ma][nb], 0, 0, 0);
    }
  }

  // Epilogue: C/D layout col(n)=lane&15, row(m)=quad*4+reg.
  const int sec = co0 >> 9;
  const int g = (co0 & 511) >> 6;
  const int bg = b * 8 + g;
  if (sec < 2) {
    unsigned short* dst = (sec == 0) ? qt : kt;
#pragma unroll
    for (int ma = 0; ma < 2; ++ma)
#pragma unroll
      for (int nb = 0; nb < 4; ++nb) {
        int n = wn + nb * 16 + l15;
        int p = (h0 + (n >> 5)) * 32 + (n & 31);
        int db = wco + ma * 16 + quad * 4;
        u16x4 pk;
#pragma unroll
        for (int r = 0; r < 4; ++r) pk[r] = bf16rne(acc[ma][nb][r]);
        *(u16x4*)(dst + ((size_t)bg * 1024 + p) * 64 + db) = pk;
      }
    // Fused reciprocal row norms.
    float ps[4];
#pragma unroll
    for (int nb = 0; nb < 4; ++nb) {
      float s = 0.f;
#pragma unroll
      for (int ma = 0; ma < 2; ++ma)
#pragma unroll
        for (int r = 0; r < 4; ++r) s = fmaf(acc[ma][nb][r], acc[ma][nb][r], s);
      s += __shfl_down(s, 32);
      s += __shfl_down(s, 16);
      ps[nb] = s;  // valid in quad==0 lanes
    }
    if (wco == 0 && quad == 0)
#pragma unroll
      for (int nb = 0; nb < 4; ++nb) Snl[wn + nb * 16 + l15] = ps[nb];
    __syncthreads();
    if (wco == 32 && quad == 0) {
      float* ndst = (sec == 0) ? rqn : rkn;
#pragma unroll
      for (int nb = 0; nb < 4; ++nb) {
        int n = wn + nb * 16 + l15;
        int p = (h0 + (n >> 5)) * 32 + (n & 31);
        ndst[bg * 1024 + p] = rsqrtf(Snl[n] + ps[nb] + SMOOTH);
      }
    }
  } else {
#pragma unroll
    for (int ma = 0; ma < 2; ++ma)
#pragma unroll
      for (int nb = 0; nb < 4; ++nb) {
        int n = wn + nb * 16 + l15;
        int p = (h0 + (n >> 5)) * 32 + (n & 31);
#pragma unroll
        for (int r = 0; r < 4; ++r) {
          int d = wco + ma * 16 + quad * 4 + r;
          vt[((size_t)bg * 64 + d) * 1024 + p] = bf16rne(acc[ma][nb][r]);
        }
      }
  }
}

// ---------------------------------------------------------------------------
// Kernel 3: attention, bf16 MFMA. Block = 64 i x (b,g); 4 waves, 16 i each.
// Normalize: S = sacc * rqn_i * rkn_j (no rcp; 1/(qn*kn+eps) ~= rqn*rkn to
// 2e-6 relative for this data -- far below bf16 rounding).
// ---------------------------------------------------------------------------
__global__ __launch_bounds__(256) void attn_mfma(
    const unsigned short* __restrict__ qt, const unsigned short* __restrict__ kt,
    const unsigned short* __restrict__ vt, const float* __restrict__ rqn,
    const float* __restrict__ rkn, unsigned short* __restrict__ aob) {
  __shared__ __align__(16) unsigned short Kl[64 * 72];  // [j][d]
  __shared__ __align__(16) unsigned short Vl[64 * 72];  // [d][j]
  __shared__ __align__(16) unsigned short Sl[64 * 72];  // [i][j], 16 rows/wave

  const int tid = threadIdx.x;
  const int lane = tid & 63, wave = tid >> 6;
  const int l15 = lane & 15, quad = lane >> 4;
  const int bg = blockIdx.x;  // fastest -> same-bg blocks share XCD L2
  const int i0 = blockIdx.y * 64;
  const int iw = i0 + wave * 16;
  const int b = bg >> 3, g = bg & 7;

  bf16x8 qf[2];
#pragma unroll
  for (int ks = 0; ks < 2; ++ks)
    qf[ks] = *(const bf16x8*)(
        qt + ((size_t)bg * 1024 + iw + l15) * 64 + ks * 32 + quad * 8);

  float rq[4];
#pragma unroll
  for (int r = 0; r < 4; ++r) rq[r] = rqn[bg * 1024 + iw + quad * 4 + r];

  f32x4 oacc[4];
  for (int nf = 0; nf < 4; ++nf) oacc[nf] = (f32x4){0.f, 0.f, 0.f, 0.f};

  unsigned short* Sw = Sl + wave * 16 * 72;

  for (int jt = 0; jt < 16; ++jt) {
    const int j0 = jt * 64;
    __syncthreads();
    for (int idx = tid; idx < 512; idx += 256) {
      int c8 = idx & 7, row = idx >> 3;
      *(u32x4*)(Kl + row * 72 + c8 * 8) =
          *(const u32x4*)(kt + ((size_t)bg * 1024 + j0 + row) * 64 + c8 * 8);
      *(u32x4*)(Vl + row * 72 + c8 * 8) =
          *(const u32x4*)(vt + ((size_t)bg * 64 + row) * 1024 + j0 + c8 * 8);
    }
    __syncthreads();

    f32x4 sacc[4];
    for (int nb = 0; nb < 4; ++nb) sacc[nb] = (f32x4){0.f, 0.f, 0.f, 0.f};
#pragma unroll
    for (int ks = 0; ks < 2; ++ks) {
#pragma unroll
      for (int nb = 0; nb < 4; ++nb) {
        bf16x8 kf = *(const bf16x8*)(Kl + (l15 + 16 * nb) * 72 + ks * 32 + quad * 8);
        sacc[nb] = __builtin_amdgcn_mfma_f32_16x16x32_bf16(
            qf[ks], kf, sacc[nb], 0, 0, 0);
      }
    }

#pragma unroll
    for (int nb = 0; nb < 4; ++nb) {
      float rk = rkn[bg * 1024 + j0 + l15 + 16 * nb];
#pragma unroll
      for (int r = 0; r < 4; ++r) {
        float s = sacc[nb][r] * (rq[r] * rk);
        Sw[(quad * 4 + r) * 72 + l15 + 16 * nb] = bf16rne(s);
      }
    }
    // Sw is wave-private: lgkmcnt orders write->read, no barrier needed.
#pragma unroll
    for (int ks2 = 0; ks2 < 2; ++ks2) {
      bf16x8 sa = *(const bf16x8*)(Sw + l15 * 72 + ks2 * 32 + quad * 8);
#pragma unroll
      for (int nf = 0; nf < 4; ++nf) {
        bf16x8 vb = *(const bf16x8*)(Vl + (l15 + 16 * nf) * 72 + ks2 * 32 + quad * 8);
        oacc[nf] = __builtin_amdgcn_mfma_f32_16x16x32_bf16(sa, vb, oacc[nf], 0, 0, 0);
      }
    }
  }

#pragma unroll
  for (int nf = 0; nf < 4; ++nf)
#pragma unroll
    for (int r = 0; r < 4; ++r) {
      int i = iw + quad * 4 + r;
      int d = l15 + 16 * nf;
      aob[((size_t)(b * 1024) + i) * 512 + g * 64 + d] = bf16rne(oacc[nf][r]);
    }
}

// ---------------------------------------------------------------------------
// Kernel 4: 1x1 conv bf16 MFMA (M=512co, N=8192p, K=512ci) + BN stats.
// Block 64co x 64p (grid 1024 = 4/CU), 4 waves of 32co x 32p.
// R10: y stored as bf16 (stats still from fp32 acc) -- halves y traffic.
// ---------------------------------------------------------------------------
__global__ __launch_bounds__(256) void conv1x1_mfma(
    const unsigned short* __restrict__ wor, const unsigned short* __restrict__ aob,
    unsigned short* __restrict__ yb, float* __restrict__ sums,
    float* __restrict__ sumsq) {
  __shared__ __align__(16) unsigned short Wl[64 * 40];  // [co][ci]
  __shared__ __align__(16) unsigned short Bl[64 * 40];  // [p][ci]

  const int tid = threadIdx.x;
  const int lane = tid & 63, wave = tid >> 6;
  const int l15 = lane & 15, quad = lane >> 4;
  const int wco = (wave & 1) * 32;
  const int wp = (wave >> 1) * 32;
  const int p0 = blockIdx.x * 64;
  const int co0 = blockIdx.y * 64;
  const int b = blockIdx.z;

  f32x4 acc[2][2];
  for (int ma = 0; ma < 2; ++ma)
    for (int nb = 0; nb < 2; ++nb) acc[ma][nb] = (f32x4){0.f, 0.f, 0.f, 0.f};

  for (int ci0 = 0; ci0 < 512; ci0 += 32) {
    __syncthreads();
    {
      int c4 = tid & 3, co = tid >> 2;
      *(u32x4*)(Wl + co * 40 + c4 * 8) =
          *(const u32x4*)(wor + (size_t)(co0 + co) * 512 + ci0 + c4 * 8);
      *(u32x4*)(Bl + co * 40 + c4 * 8) =
          *(const u32x4*)(aob + ((size_t)(b * 1024) + p0 + co) * 512 + ci0 + c4 * 8);
    }
    __syncthreads();

    bf16x8 af[2], bf[2];
#pragma unroll
    for (int ma = 0; ma < 2; ++ma)
      af[ma] = *(const bf16x8*)(Wl + (wco + ma * 16 + l15) * 40 + quad * 8);
#pragma unroll
    for (int nb = 0; nb < 2; ++nb)
      bf[nb] = *(const bf16x8*)(Bl + (wp + nb * 16 + l15) * 40 + quad * 8);
#pragma unroll
    for (int ma = 0; ma < 2; ++ma)
#pragma unroll
      for (int nb = 0; nb < 2; ++nb)
        acc[ma][nb] = __builtin_amdgcn_mfma_f32_16x16x32_bf16(
            af[ma], bf[nb], acc[ma][nb], 0, 0, 0);
  }

#pragma unroll
  for (int ma = 0; ma < 2; ++ma)
#pragma unroll
    for (int r = 0; r < 4; ++r) {
      int co = co0 + wco + ma * 16 + quad * 4 + r;
      float s1 = 0.f, s2 = 0.f;
#pragma unroll
      for (int nb = 0; nb < 2; ++nb) {
        float v = acc[ma][nb][r];
        yb[((size_t)(b * 512) + co) * 1024 + p0 + wp + nb * 16 + l15] = bf16rne(v);
        s1 += v;
        s2 = fmaf(v, v, s2);
      }
      for (int off = 8; off >= 1; off >>= 1) {
        s1 += __shfl_down(s1, off, 16);
        s2 += __shfl_down(s2, off, 16);
      }
      if (l15 == 0) {
        atomicAdd(&sums[co], s1);
        atomicAdd(&sumsq[co], s2);
      }
    }
}

// ---------------------------------------------------------------------------
// Kernel 5: BatchNorm (batch stats, biased var) + ReLU. bf16 in, fp32 out.
// ---------------------------------------------------------------------------
__global__ void bn_kernel(const unsigned short* __restrict__ yb,
                          const float* __restrict__ sums,
                          const float* __restrict__ sumsq,
                          const float* __restrict__ gamma,
                          const float* __restrict__ beta,
                          float* __restrict__ out) {
  int idx = blockIdx.x * 256 + threadIdx.x;  // 1048576 groups of 4
  int c = (idx >> 8) & 511;
  u16x4 vb = *(const u16x4*)(yb + (size_t)idx * 4);
  float mean = sums[c] * (1.f / 8192.f);
  float var = sumsq[c] * (1.f / 8192.f) - mean * mean;
  float sc = gamma[c] * rsqrtf(var + BN_EPS);
  float sh = beta[c] - mean * sc;
  float4 r;
  r.x = fmaxf(0.f, fmaf(b2f(vb[0]), sc, sh));
  r.y = fmaxf(0.f, fmaf(b2f(vb[1]), sc, sh));
  r.z = fmaxf(0.f, fmaf(b2f(vb[2]), sc, sh));
  r.w = fmaxf(0.f, fmaf(b2f(vb[3]), sc, sh));
  ((float4*)out)[idx] = r;
}

// ---------------------------------------------------------------------------
extern "C" void kernel_launch(void* const* d_in, const int* in_sizes, int n_in,
                              void* d_out, int out_size, void* d_ws,
                              size_t ws_size, hipStream_t stream) {
  const float* x = (const float*)d_in[0];
  const float* wq = (const float*)d_in[1];
  const float* wo = (const float*)d_in[2];
  const float* gamma = (const float*)d_in[3];
  const float* beta = (const float*)d_in[4];
  float* out = (float*)d_out;

  // Workspace layout (~67 MB, all 16B aligned)
  unsigned short* qt = (unsigned short*)d_ws;          // [64][1024][64]
  unsigned short* kt = qt + (size_t)4194304;
  unsigned short* vt = kt + (size_t)4194304;           // [64][64][1024]
  unsigned short* aob = vt + (size_t)4194304;          // [8][1024][512]
  unsigned short* wqr2 = aob + (size_t)4194304;        // [16][24][4][9][64][8]
  unsigned short* wor = wqr2 + (size_t)7077888;        // [512][512]
  unsigned short* xrp2 = wor + (size_t)262144;         // [16][4][8][34][34][8]+pad
  float* rqn = (float*)(xrp2 + (size_t)4736000);       // [64][1024] (1/qn)
  float* rkn = rqn + 65536;
  unsigned short* yb = (unsigned short*)(rkn + 65536); // [8][512][1024] bf16
  float* sums = (float*)(yb + (size_t)4194304);
  float* sumsq = sums + 512;

  // Zero padded-x buffer (borders stay 0; repack_x fills the interior).
  hipMemsetAsync(xrp2, 0, (size_t)4736000 * 2, stream);
  repack_w<<<dim3(3072), 256, 0, stream>>>(wq, wqr2);
  repack_x<<<dim3(512), 256, 0, stream>>>(x, xrp2);
  repack_wo<<<dim3(1024), 256, 0, stream>>>(wo, wor, sums, sumsq);
  conv3x3_mfma<<<dim3(8, 24, 8), 256, 0, stream>>>(wqr2, xrp2, qt, kt, vt, rqn, rkn);
  attn_mfma<<<dim3(64, 16), 256, 0, stream>>>(qt, kt, vt, rqn, rkn, aob);
  conv1x1_mfma<<<dim3(16, 8, 8), 256, 0, stream>>>(wor, aob, yb, sums, sumsq);
  bn_kernel<<<dim3(4096), 256, 0, stream>>>(yb, sums, sumsq, gamma, beta, out);
}